// Round 9
// baseline (155.799 us; speedup 1.0000x reference)
//
#include <hip/hip_runtime.h>
#include <hip/hip_bf16.h>
#include <cstdint>
#include <cstddef>

// ---------- types ----------
typedef __bf16 bf16x8 __attribute__((ext_vector_type(8)));
typedef float  f32x4  __attribute__((ext_vector_type(4)));

static constexpr int B  = 16;
static constexpr int T  = 4096;
static constexpr int D  = 256;
static constexpr int M  = B * T;          // 65536 rows
static constexpr int SEGS = 64;           // segments along T
static constexpr int SEGL = T / SEGS;     // 64 steps per segment

// raw barrier (no vmcnt drain) + compiler memory fences; LGKM0 for LDS
// producer->consumer edges only. This keeps global prefetches in flight
// across barriers (the __syncthreads vmcnt(0) drain was a structural stall).
#define RBAR() do { asm volatile("" ::: "memory"); \
                    __builtin_amdgcn_s_barrier();  \
                    asm volatile("" ::: "memory"); } while (0)
#define LGKM0() asm volatile("s_waitcnt lgkmcnt(0)" ::: "memory")

// fast sigmoid: v_exp_f32 + v_rcp_f32 instead of IEEE div (~10 instrs).
__device__ __forceinline__ float sigmoid_fast(float v) {
    return __builtin_amdgcn_rcpf(1.0f + __expf(-v));
}

// ---------- build fragment-major interleaved bf16 weights ----------
// Wp_s element layout: [(ks*32 + fg)*64 + lane] * 8 bf16 elems, where
//   fg = vcol>>4 (0..31), lane = kg*16 + rl, elem ko in [0,8)
//   stored value = W_{s,gate}[rc][ks*32 + kg*8 + ko]
// vcol decomposition: w = fg>>2 (col-wave 0..7), f = fg&3, q = f>>1,
//   gate = f&1, rc = w*32 + 2*rl + q  (lane rl holds 2 ADJACENT real cols)
__global__ void cvt_w(const float* __restrict__ W0, const float* __restrict__ W1,
                      const float* __restrict__ W2, const float* __restrict__ W3,
                      __bf16* __restrict__ wp) {
    int i = blockIdx.x * blockDim.x + threadIdx.x;   // 0..32767
    int s    = i >> 14;
    int r    = i & 16383;
    int ks   = r >> 11;          // 0..7
    int fg   = (r >> 6) & 31;    // 0..31
    int lane = r & 63;
    int kg = lane >> 4, rl = lane & 15;
    int w = fg >> 2, f = fg & 3;
    int q = f >> 1, gate = f & 1;
    int rc = w * 32 + 2 * rl + q;
    const float* src = (s == 0) ? (gate ? W1 : W0) : (gate ? W3 : W2);
    const float* p = src + (size_t)rc * 256 + ks * 32 + kg * 8;
    bf16x8 o;
#pragma unroll
    for (int j = 0; j < 8; ++j) o[j] = (__bf16)p[j];
    *reinterpret_cast<bf16x8*>(wp + (size_t)s * 131072 +
                               ((size_t)((ks * 32 + fg) * 64 + lane)) * 8) = o;
}

// ---------- fused two-stage gated-linear + per-segment scan compose ----------
// DOUBLE-TILE persistent block: grid 512, each block processes 2 consecutive
// 64-row tiles (= 2 (batch,segment) pairs) through two 32 KiB LDS tiles.
// Tile B's x-loads are issued after tile A's epilogue-1 (acc dead) and stay
// in flight across RAW barriers through A's whole tail (~1000 cyc cover).
// Weight L2 traffic halves vs single-tile (512 KB per block, 512 blocks).
// Per tile: x (bf16, staged) -> h (bf16, in-place) -> ftile (f32 [32][256],
// row-split) -> per-segment (A,Mx) compose. 8 waves; wave w owns real cols
// [w*32,+32), 2 adjacent/lane. B streamed from L2, 2-deep pipelined.
__launch_bounds__(512, 4)
__global__ void gln_fused(const float* __restrict__ x,
                          const __bf16* __restrict__ wp,
                          const float* __restrict__ b0, const float* __restrict__ b1,
                          const float* __restrict__ b2, const float* __restrict__ b3,
                          float* __restrict__ out,
                          float2* __restrict__ seg_am) {
    __shared__ char tiles[2][32768];       // [64][256] bf16 each, chunk-XOR swz

    const int tid  = threadIdx.x;          // 0..511
    const int lane = tid & 63;
    const int wid  = tid >> 6;             // 0..7
    const int rl   = lane & 15;
    const int kg   = lane >> 4;            // 0..3
    const int row0A = blockIdx.x * 128;
    const int row0B = row0A + 64;

    const __bf16* wv0 = wp + ((size_t)(wid * 4) * 64 + lane) * 8;
    const __bf16* wv1 = wv0 + 131072;

    const int r   = tid >> 3;              // staging row 0..63
    const int c0  = tid & 7;               // staging base 16B-chunk
    const int rc0 = wid * 32 + 2 * rl;     // even real col of this lane

    bf16x8 bbuf[2][4];
    auto loadB = [&](int p, const __bf16* wvb, int ks) {
#pragma unroll
        for (int f = 0; f < 4; ++f)
            bbuf[p][f] = *reinterpret_cast<const bf16x8*>(wvb + ks * 16384 + f * 512);
    };

    float4 xr[4][2];                       // in-flight x rows (32 VGPR)
    auto issue_x = [&](int row0t) {
        const float* xp = x + (size_t)(row0t + r) * 256;
#pragma unroll
        for (int ci = 0; ci < 4; ++ci) {
            const float4* p = reinterpret_cast<const float4*>(xp + (c0 + ci * 8) * 8);
            xr[ci][0] = p[0];
            xr[ci][1] = p[1];
        }
    };
    auto write_x = [&](char* tbuf) {
#pragma unroll
        for (int ci = 0; ci < 4; ++ci) {
            int ck = c0 + ci * 8;          // logical chunk 0..31
            int pc = ck ^ ((r & 7) << 2);
            bf16x8 o = { (__bf16)xr[ci][0].x, (__bf16)xr[ci][0].y,
                         (__bf16)xr[ci][0].z, (__bf16)xr[ci][0].w,
                         (__bf16)xr[ci][1].x, (__bf16)xr[ci][1].y,
                         (__bf16)xr[ci][1].z, (__bf16)xr[ci][1].w };
            *reinterpret_cast<bf16x8*>(&tbuf[r * 512 + pc * 16]) = o;
        }
    };

    f32x4 acc[4][4];
    // one GEMM stage: A from LDS (64 rows, K=256), B 2-deep pipelined from L2.
    auto run_stage = [&](const char* alds, const __bf16* wvb) {
#pragma unroll
        for (int m = 0; m < 4; ++m)
#pragma unroll
            for (int f = 0; f < 4; ++f) acc[m][f] = (f32x4){0.f, 0.f, 0.f, 0.f};
#pragma unroll
        for (int ks = 0; ks < 8; ++ks) {
            if (ks < 7) loadB((ks + 1) & 1, wvb, ks + 1);   // prefetch next ks
            bf16x8 aR[4];
#pragma unroll
            for (int m = 0; m < 4; ++m) {
                int row = m * 16 + rl;
                int pc  = (ks * 4 + kg) ^ ((row & 7) << 2);
                aR[m] = *reinterpret_cast<const bf16x8*>(&alds[row * 512 + pc * 16]);
            }
#pragma unroll
            for (int m = 0; m < 4; ++m)
#pragma unroll
                for (int f = 0; f < 4; ++f)
                    acc[m][f] = __builtin_amdgcn_mfma_f32_16x16x32_bf16(
                        aR[m], bbuf[ks & 1][f], acc[m][f], 0, 0, 0);
        }
    };

    // epilogue 0: h = (l0+b0)*sigmoid(l1+b1), packed u32 -> LDS in place
    auto epi0 = [&](char* tbuf) {
        float2 bb0 = *reinterpret_cast<const float2*>(b0 + rc0);
        float2 bb1 = *reinterpret_cast<const float2*>(b1 + rc0);
        int cb  = rc0 * 2;
        int ck  = cb >> 4;
        int off = cb & 15;
#pragma unroll
        for (int m = 0; m < 4; ++m)
#pragma unroll
            for (int j = 0; j < 4; ++j) {
                int row = m * 16 + kg * 4 + j;
                float he = (acc[m][0][j] + bb0.x) * sigmoid_fast(acc[m][1][j] + bb1.x);
                float ho = (acc[m][2][j] + bb0.y) * sigmoid_fast(acc[m][3][j] + bb1.y);
                unsigned short ue = __builtin_bit_cast(unsigned short, (__bf16)he);
                unsigned short uo = __builtin_bit_cast(unsigned short, (__bf16)ho);
                unsigned int u = ((unsigned int)uo << 16) | (unsigned int)ue;
                int pc = ck ^ ((row & 7) << 2);
                *reinterpret_cast<unsigned int*>(&tbuf[row * 512 + pc * 16 + off]) = u;
            }
    };

    float2 ov[16];
    // epilogue 1: gated output -> ov regs (acc dies here)
    auto epi1 = [&]() {
        float2 bb2 = *reinterpret_cast<const float2*>(b2 + rc0);
        float2 bb3 = *reinterpret_cast<const float2*>(b3 + rc0);
#pragma unroll
        for (int m = 0; m < 4; ++m)
#pragma unroll
            for (int j = 0; j < 4; ++j) {
                float he = (acc[m][0][j] + bb2.x) * sigmoid_fast(acc[m][1][j] + bb3.x);
                float ho = (acc[m][2][j] + bb2.y) * sigmoid_fast(acc[m][3][j] + bb3.y);
                float2 o; o.x = he; o.y = ho;
                ov[m * 4 + j] = o;
            }
    };

    // tail: row-split ftile + seg compose + global stores. Entered AFTER a
    // barrier guaranteeing the tile's h reads are consumed.
    auto tail = [&](char* tbuf, int row0t) {
        float* ftile = reinterpret_cast<float*>(tbuf);   // [32][256] f32
#pragma unroll
        for (int m = 0; m < 2; ++m)
#pragma unroll
            for (int j = 0; j < 4; ++j) {
                int row = m * 16 + kg * 4 + j;
                int col = rc0 ^ ((row & 7) << 2);
                *reinterpret_cast<float2*>(&ftile[row * 256 + col]) = ov[m * 4 + j];
            }
        LGKM0(); RBAR();
        const int batch = row0t >> 12;
        const int t0    = row0t & 4095;
        const int seg   = t0 >> 6;
        float A = 0.f, Mx = -1e30f;
        int cc = 0;
        if (tid < 256) {
            cc = (tid + t0) & 255;
#pragma unroll 8
            for (int i = 0; i < 32; ++i) {
                int col = ((cc + i) & 255) ^ ((i & 7) << 2);
                float v = ftile[i * 256 + col];
                A += v;
                Mx = fmaxf(Mx + v, 0.f);
            }
        }
        RBAR();                    // part-1 reads consumed before overwrite
#pragma unroll
        for (int m = 2; m < 4; ++m)
#pragma unroll
            for (int j = 0; j < 4; ++j) {
                int row = m * 16 + kg * 4 + j;
                int pr  = row & 31;
                int col = rc0 ^ ((pr & 7) << 2);
                *reinterpret_cast<float2*>(&ftile[pr * 256 + col]) = ov[m * 4 + j];
            }
        // global stores (un-drained across raw barriers; overlap the compose)
#pragma unroll
        for (int m = 0; m < 4; ++m)
#pragma unroll
            for (int j = 0; j < 4; ++j) {
                int row = m * 16 + kg * 4 + j;
                *reinterpret_cast<float2*>(out + (size_t)(row0t + row) * 256 + rc0) =
                    ov[m * 4 + j];
            }
        LGKM0(); RBAR();
        if (tid < 256) {
#pragma unroll 8
            for (int i = 32; i < 64; ++i) {
                int pr  = i - 32;
                int col = ((cc + i) & 255) ^ ((pr & 7) << 2);
                float v = ftile[pr * 256 + col];
                A += v;
                Mx = fmaxf(Mx + v, 0.f);
            }
            float2 o; o.x = A; o.y = Mx;
            seg_am[(size_t)(batch * SEGS + seg) * 256 + tid] = o;
        }
    };

    // ===================== flow =====================
    // tile A staging
    issue_x(row0A);
    write_x(tiles[0]);
    loadB(0, wv0, 0);              // stays in flight across raw barrier
    LGKM0(); RBAR();

    // ---- tile A ----
    run_stage(tiles[0], wv0);
    loadB(0, wv1, 0);              // stage-1 ks0 prefetch (survives barriers)
    RBAR();                        // x reads consumed; safe to overwrite
    epi0(tiles[0]);
    LGKM0(); RBAR();
    run_stage(tiles[0], wv1);
    epi1();                        // acc -> ov; acc dead
    issue_x(row0B);                // tile-B x loads fly through A's tail
    RBAR();                        // h reads consumed; tileA reusable
    tail(tiles[0], row0A);

    // stage tile B (xr landed during A's tail; precise vmcnt wait at use)
    write_x(tiles[1]);
    loadB(0, wv0, 0);
    LGKM0(); RBAR();

    // ---- tile B ----
    run_stage(tiles[1], wv0);
    loadB(0, wv1, 0);
    RBAR();
    epi0(tiles[1]);
    LGKM0(); RBAR();
    run_stage(tiles[1], wv1);
    epi1();
    RBAR();
    tail(tiles[1], row0B);
    // no trailing barrier: stores drain at wave retirement
}

// ---------- scan apply with integrated boundary lookback ----------
// Block = one (batch, seg) x 256 cols. Redundantly composes seg_am[0..seg)
// (<=63 serial fmax steps, L2/L3-resident).
__global__ void scan_apply(float* __restrict__ bio,
                           const float2* __restrict__ seg_am,
                           const float* __restrict__ hidden,
                           float* __restrict__ last) {
    int tid   = blockIdx.x * blockDim.x + threadIdx.x;
    int c     = tid & 255;
    int rest  = tid >> 8;
    int batch = rest & 15;
    int seg   = rest >> 4;
    float s = hidden[batch * 256 + ((c + 255) & 255)];
    const float2* am = seg_am + ((size_t)batch * SEGS) * 256 + c;
    for (int k = 0; k < seg; ++k) {
        float2 a = am[(size_t)k * 256];
        s = fmaxf(s + a.x, a.y);
    }
    float* base = bio + (size_t)batch * T * D;
    int t0 = seg * SEGL;
#pragma unroll 8
    for (int i = 0; i < SEGL; ++i) {
        int t = t0 + i;
        size_t idx = (size_t)t * 256 + ((c + t) & 255);
        float v = base[idx];
        s = fmaxf(s + v, 0.f);
        base[idx] = s;
    }
    if (seg == SEGS - 1) last[batch * 256 + ((c + 255) & 255)] = s;
}

// ---------- launch ----------
extern "C" void kernel_launch(void* const* d_in, const int* in_sizes, int n_in,
                              void* d_out, int out_size, void* d_ws, size_t ws_size,
                              hipStream_t stream) {
    const float* x      = (const float*)d_in[0];
    const float* hidden = (const float*)d_in[1];
    const float* W0 = (const float*)d_in[2];
    const float* b0 = (const float*)d_in[3];
    const float* W1 = (const float*)d_in[4];
    const float* b1 = (const float*)d_in[5];
    const float* W2 = (const float*)d_in[6];
    const float* b2 = (const float*)d_in[7];
    const float* W3 = (const float*)d_in[8];
    const float* b3 = (const float*)d_in[9];

    float* out  = (float*)d_out;
    float* last = out + (size_t)M * D;

    char* ws = (char*)d_ws;
    __bf16* wpb    = (__bf16*)ws;                 // 524,288 B (Wp0, Wp1)
    float2* seg_am = (float2*)(ws + 524288);      // 2,097,152 B

    cvt_w<<<128, 256, 0, stream>>>(W0, W1, W2, W3, wpb);
    gln_fused<<<M / 128, 512, 0, stream>>>(x, wpb, b0, b1, b2, b3, out, seg_am);
    scan_apply<<<(B * D * SEGS) / 256, 256, 0, stream>>>(out, seg_am, hidden, last);
}

// Round 10
// 84.036 us; speedup vs baseline: 1.8540x; 1.8540x over previous
//
#include <hip/hip_runtime.h>
#include <hip/hip_bf16.h>
#include <cstdint>
#include <cstddef>

// ---------- types ----------
typedef __bf16 bf16x8 __attribute__((ext_vector_type(8)));
typedef float  f32x4  __attribute__((ext_vector_type(4)));

static constexpr int B  = 16;
static constexpr int T  = 4096;
static constexpr int D  = 256;
static constexpr int M  = B * T;          // 65536 rows
static constexpr int SEGS = 64;           // segments along T
static constexpr int SEGL = T / SEGS;     // 64 steps per segment

// raw barrier (no vmcnt(0) drain) + compiler fences; LGKM0 fences LDS
// producer->consumer edges. Global prefetches/stores stay in flight across
// barriers; their consumers are guarded by compiler-inserted vmcnt data-dep
// waits, and 'out' is never re-read in-kernel.
#define RBAR() do { asm volatile("" ::: "memory"); \
                    __builtin_amdgcn_s_barrier();  \
                    asm volatile("" ::: "memory"); } while (0)
#define LGKM0() asm volatile("s_waitcnt lgkmcnt(0)" ::: "memory")

// fast sigmoid: v_exp_f32 + v_rcp_f32 instead of IEEE div (~10 instrs).
__device__ __forceinline__ float sigmoid_fast(float v) {
    return __builtin_amdgcn_rcpf(1.0f + __expf(-v));
}

// ---------- build fragment-major interleaved bf16 weights ----------
// Wp_s element layout: [(ks*32 + fg)*64 + lane] * 8 bf16 elems, where
//   fg = vcol>>4 (0..31), lane = kg*16 + rl, elem ko in [0,8)
//   stored value = W_{s,gate}[rc][ks*32 + kg*8 + ko]
// vcol decomposition: w = fg>>2 (col-wave 0..7), f = fg&3, q = f>>1,
//   gate = f&1, rc = w*32 + 2*rl + q  (lane rl holds 2 ADJACENT real cols)
__global__ void cvt_w(const float* __restrict__ W0, const float* __restrict__ W1,
                      const float* __restrict__ W2, const float* __restrict__ W3,
                      __bf16* __restrict__ wp) {
    int i = blockIdx.x * blockDim.x + threadIdx.x;   // 0..32767
    int s    = i >> 14;
    int r    = i & 16383;
    int ks   = r >> 11;          // 0..7
    int fg   = (r >> 6) & 31;    // 0..31
    int lane = r & 63;
    int kg = lane >> 4, rl = lane & 15;
    int w = fg >> 2, f = fg & 3;
    int q = f >> 1, gate = f & 1;
    int rc = w * 32 + 2 * rl + q;
    const float* src = (s == 0) ? (gate ? W1 : W0) : (gate ? W3 : W2);
    const float* p = src + (size_t)rc * 256 + ks * 32 + kg * 8;
    bf16x8 o;
#pragma unroll
    for (int j = 0; j < 8; ++j) o[j] = (__bf16)p[j];
    *reinterpret_cast<bf16x8*>(wp + (size_t)s * 131072 +
                               ((size_t)((ks * 32 + fg) * 64 + lane)) * 8) = o;
}

// ---------- fused two-stage gated-linear + per-segment scan compose ----------
// EXACT r8 structure (single 64-row tile, 512 thr / 8 waves, 32 KiB LDS,
// verified 63 us) with __syncthreads() replaced by RBAR/LGKM0 so in-flight
// global ops (bbuf prefetches, output stores) are NOT drained at barriers.
// Per tile: x (bf16, staged) -> h (bf16, in-place) -> ftile (f32 [32][256],
// row-split) -> per-segment (A,Mx) compose. Wave w owns real cols [w*32,+32).
// NOTE (r9 lesson): do NOT hold global-load staging arrays live across the
// tail's barriers — it spills to scratch and triples HBM traffic.
__launch_bounds__(512, 4)
__global__ void gln_fused(const float* __restrict__ x,
                          const __bf16* __restrict__ wp,
                          const float* __restrict__ b0, const float* __restrict__ b1,
                          const float* __restrict__ b2, const float* __restrict__ b3,
                          float* __restrict__ out,
                          float2* __restrict__ seg_am) {
    __shared__ char tile[32768];           // [64][256] bf16, chunk-XOR swizzle

    const int tid  = threadIdx.x;          // 0..511
    const int lane = tid & 63;
    const int wid  = tid >> 6;             // 0..7
    const int rl   = lane & 15;
    const int kg   = lane >> 4;            // 0..3
    const int row0 = blockIdx.x * 64;

    const __bf16* wv0 = wp + ((size_t)(wid * 4) * 64 + lane) * 8;
    const __bf16* wv1 = wv0 + 131072;

    bf16x8 bbuf[2][4];
    auto loadB = [&](int p, const __bf16* wvb, int ks) {
#pragma unroll
        for (int f = 0; f < 4; ++f)
            bbuf[p][f] = *reinterpret_cast<const bf16x8*>(wvb + ks * 16384 + f * 512);
    };

    // ---- stage x rows [row0, row0+64) into LDS as bf16 ----
    {
        int r  = tid >> 3;         // 0..63
        int c0 = tid & 7;          // base 16B-chunk
        const float* xr = x + (size_t)(row0 + r) * 256;
        float4 xa[4][2];
#pragma unroll
        for (int ci = 0; ci < 4; ++ci) {
            const float4* p = reinterpret_cast<const float4*>(xr + (c0 + ci * 8) * 8);
            xa[ci][0] = p[0];
            xa[ci][1] = p[1];
        }
#pragma unroll
        for (int ci = 0; ci < 4; ++ci) {
            int ck = c0 + ci * 8;  // logical chunk 0..31
            int pc = ck ^ ((r & 7) << 2);
            bf16x8 o = { (__bf16)xa[ci][0].x, (__bf16)xa[ci][0].y,
                         (__bf16)xa[ci][0].z, (__bf16)xa[ci][0].w,
                         (__bf16)xa[ci][1].x, (__bf16)xa[ci][1].y,
                         (__bf16)xa[ci][1].z, (__bf16)xa[ci][1].w };
            *reinterpret_cast<bf16x8*>(&tile[r * 512 + pc * 16]) = o;
        }
    }
    loadB(0, wv0, 0);              // stays in flight across raw barrier
    LGKM0(); RBAR();

    f32x4 acc[4][4];

    // one GEMM stage: A from LDS (64 rows, K=256), B 2-deep pipelined from L2.
    auto run_stage = [&](const __bf16* wvb) {
#pragma unroll
        for (int m = 0; m < 4; ++m)
#pragma unroll
            for (int f = 0; f < 4; ++f) acc[m][f] = (f32x4){0.f, 0.f, 0.f, 0.f};
#pragma unroll
        for (int ks = 0; ks < 8; ++ks) {
            if (ks < 7) loadB((ks + 1) & 1, wvb, ks + 1);   // prefetch next ks
            bf16x8 aR[4];
#pragma unroll
            for (int m = 0; m < 4; ++m) {
                int row = m * 16 + rl;
                int pc  = (ks * 4 + kg) ^ ((row & 7) << 2);
                aR[m] = *reinterpret_cast<const bf16x8*>(&tile[row * 512 + pc * 16]);
            }
#pragma unroll
            for (int m = 0; m < 4; ++m)
#pragma unroll
                for (int f = 0; f < 4; ++f)
                    acc[m][f] = __builtin_amdgcn_mfma_f32_16x16x32_bf16(
                        aR[m], bbuf[ks & 1][f], acc[m][f], 0, 0, 0);
        }
    };

    const int rc0 = wid * 32 + 2 * rl;     // even real col of this lane

    // ---- stage 0: h = (x@W0^T+b0) * sigmoid(x@W1^T+b1) ----
    run_stage(wv0);
    loadB(0, wv1, 0);              // stage-1 ks0 prefetch (survives barriers)
    RBAR();                        // x reads consumed (data-dep); overwrite ok
    {
        float2 bb0 = *reinterpret_cast<const float2*>(b0 + rc0);
        float2 bb1 = *reinterpret_cast<const float2*>(b1 + rc0);
        int cb  = rc0 * 2;                 // byte col (4-aligned)
        int ck  = cb >> 4;                 // logical chunk
        int off = cb & 15;
#pragma unroll
        for (int m = 0; m < 4; ++m)
#pragma unroll
            for (int j = 0; j < 4; ++j) {
                int row = m * 16 + kg * 4 + j;
                float he = (acc[m][0][j] + bb0.x) * sigmoid_fast(acc[m][1][j] + bb1.x);
                float ho = (acc[m][2][j] + bb0.y) * sigmoid_fast(acc[m][3][j] + bb1.y);
                unsigned short ue = __builtin_bit_cast(unsigned short, (__bf16)he);
                unsigned short uo = __builtin_bit_cast(unsigned short, (__bf16)ho);
                unsigned int u = ((unsigned int)uo << 16) | (unsigned int)ue;
                int pc = ck ^ ((row & 7) << 2);
                *reinterpret_cast<unsigned int*>(&tile[row * 512 + pc * 16 + off]) = u;
            }
    }
    LGKM0(); RBAR();

    // ---- stage 1: out = (h@W2^T+b2) * sigmoid(h@W3^T+b3) ----
    run_stage(wv1);

    // epilogue: gated values -> regs only
    float2 ov[16];
    {
        float2 bb2 = *reinterpret_cast<const float2*>(b2 + rc0);
        float2 bb3 = *reinterpret_cast<const float2*>(b3 + rc0);
#pragma unroll
        for (int m = 0; m < 4; ++m)
#pragma unroll
            for (int j = 0; j < 4; ++j) {
                float he = (acc[m][0][j] + bb2.x) * sigmoid_fast(acc[m][1][j] + bb3.x);
                float ho = (acc[m][2][j] + bb2.y) * sigmoid_fast(acc[m][3][j] + bb3.y);
                float2 o; o.x = he; o.y = ho;
                ov[m * 4 + j] = o;
            }
    }
    RBAR();                        // h reads consumed; tile reusable

    // ---- row-split ftile + fused scan_seg compose (state in regs) ----
    float* ftile = reinterpret_cast<float*>(tile);   // [32][256] f32 = 32 KiB
#pragma unroll
    for (int m = 0; m < 2; ++m)
#pragma unroll
        for (int j = 0; j < 4; ++j) {
            int row = m * 16 + kg * 4 + j;
            int col = rc0 ^ ((row & 7) << 2);
            *reinterpret_cast<float2*>(&ftile[row * 256 + col]) = ov[m * 4 + j];
        }
    LGKM0(); RBAR();

    const int batch = row0 >> 12;          // row0 / T
    const int t0    = row0 & 4095;
    const int seg   = t0 >> 6;
    float A = 0.f, Mx = -1e30f;
    int cc = 0;
    if (tid < 256) {
        cc = (tid + t0) & 255;
#pragma unroll 8
        for (int i = 0; i < 32; ++i) {
            int col = ((cc + i) & 255) ^ ((i & 7) << 2);
            float v = ftile[i * 256 + col];
            A += v;
            Mx = fmaxf(Mx + v, 0.f);
        }
    }
    RBAR();                        // part-1 reads consumed before overwrite
#pragma unroll
    for (int m = 2; m < 4; ++m)
#pragma unroll
        for (int j = 0; j < 4; ++j) {
            int row = m * 16 + kg * 4 + j;
            int pr  = row & 31;
            int col = rc0 ^ ((pr & 7) << 2);
            *reinterpret_cast<float2*>(&ftile[pr * 256 + col]) = ov[m * 4 + j];
        }

    // global stores: NOT drained by the raw barrier below; overlap compose
#pragma unroll
    for (int m = 0; m < 4; ++m)
#pragma unroll
        for (int j = 0; j < 4; ++j) {
            int row = m * 16 + kg * 4 + j;
            *reinterpret_cast<float2*>(out + (size_t)(row0 + row) * 256 + rc0) =
                ov[m * 4 + j];
        }
    LGKM0(); RBAR();

    if (tid < 256) {
#pragma unroll 8
        for (int i = 32; i < 64; ++i) {
            int pr  = i - 32;
            int col = ((cc + i) & 255) ^ ((pr & 7) << 2);
            float v = ftile[pr * 256 + col];
            A += v;
            Mx = fmaxf(Mx + v, 0.f);
        }
        float2 o; o.x = A; o.y = Mx;
        seg_am[(size_t)(batch * SEGS + seg) * 256 + tid] = o;
    }
    // stores drain at wave retirement
}

// ---------- scan apply with integrated boundary lookback ----------
// Block = one (batch, seg) x 256 cols. Redundantly composes seg_am[0..seg)
// (<=63 serial fmax steps, L2/L3-resident).
__global__ void scan_apply(float* __restrict__ bio,
                           const float2* __restrict__ seg_am,
                           const float* __restrict__ hidden,
                           float* __restrict__ last) {
    int tid   = blockIdx.x * blockDim.x + threadIdx.x;
    int c     = tid & 255;
    int rest  = tid >> 8;
    int batch = rest & 15;
    int seg   = rest >> 4;
    float s = hidden[batch * 256 + ((c + 255) & 255)];
    const float2* am = seg_am + ((size_t)batch * SEGS) * 256 + c;
    for (int k = 0; k < seg; ++k) {
        float2 a = am[(size_t)k * 256];
        s = fmaxf(s + a.x, a.y);
    }
    float* base = bio + (size_t)batch * T * D;
    int t0 = seg * SEGL;
#pragma unroll 8
    for (int i = 0; i < SEGL; ++i) {
        int t = t0 + i;
        size_t idx = (size_t)t * 256 + ((c + t) & 255);
        float v = base[idx];
        s = fmaxf(s + v, 0.f);
        base[idx] = s;
    }
    if (seg == SEGS - 1) last[batch * 256 + ((c + 255) & 255)] = s;
}

// ---------- launch ----------
extern "C" void kernel_launch(void* const* d_in, const int* in_sizes, int n_in,
                              void* d_out, int out_size, void* d_ws, size_t ws_size,
                              hipStream_t stream) {
    const float* x      = (const float*)d_in[0];
    const float* hidden = (const float*)d_in[1];
    const float* W0 = (const float*)d_in[2];
    const float* b0 = (const float*)d_in[3];
    const float* W1 = (const float*)d_in[4];
    const float* b1 = (const float*)d_in[5];
    const float* W2 = (const float*)d_in[6];
    const float* b2 = (const float*)d_in[7];
    const float* W3 = (const float*)d_in[8];
    const float* b3 = (const float*)d_in[9];

    float* out  = (float*)d_out;
    float* last = out + (size_t)M * D;

    char* ws = (char*)d_ws;
    __bf16* wpb    = (__bf16*)ws;                 // 524,288 B (Wp0, Wp1)
    float2* seg_am = (float2*)(ws + 524288);      // 2,097,152 B

    cvt_w<<<128, 256, 0, stream>>>(W0, W1, W2, W3, wpb);
    gln_fused<<<M / 64, 512, 0, stream>>>(x, wpb, b0, b1, b2, b3, out, seg_am);
    scan_apply<<<(B * D * SEGS) / 256, 256, 0, stream>>>(out, seg_am, hidden, last);
}